// Round 3
// baseline (1857.382 us; speedup 1.0000x reference)
//
#include <hip/hip_runtime.h>
#include <hip/hip_bf16.h>

// ---- types ----
typedef _Float16 f16x8 __attribute__((ext_vector_type(8)));
typedef _Float16 f16x4 __attribute__((ext_vector_type(4)));
typedef float f32x4 __attribute__((ext_vector_type(4)));

// Problem constants: S=2048, B=32, D_IN=512, H=1024, PROJ=512, L=2
#define SEQ 2048
#define BATCH 32
#define DIN 512
#define HID 1024
#define PROJ 512
#define ROWS (SEQ*BATCH)          // 65536
#define G3H (3*HID)               // 3072

#define AS1(p) ((const __attribute__((address_space(1))) void*)(p))
#define AS3(p) ((__attribute__((address_space(3))) void*)(p))

// ---------------- fp32 -> fp16 conversion ----------------
__global__ __launch_bounds__(256)
void cvt_f32_f16(const float* __restrict__ in, _Float16* __restrict__ out, int n4)
{
    int i = blockIdx.x * 256 + threadIdx.x;
    if (i >= n4) return;
    float4 v = ((const float4*)in)[i];
    f16x4 o;
    o[0] = (_Float16)v.x; o[1] = (_Float16)v.y;
    o[2] = (_Float16)v.z; o[3] = (_Float16)v.w;
    ((f16x4*)out)[i] = o;
}

// ---------------- GEMM (m97 structure): C(M,N) = A(M,K) * B(N,K)^T ----------
// A,B fp16 row-major; fp32 accum via mfma_f32_16x16x32_f16.
// LDS: linear [128][32] fp16 (8 KiB each), staged with global_load_lds w=16.
// 4 waves, each owns a 64x64 output sub-tile (4x4 fragments of 16x16).
// MODE 0: epilogue +bias, col<HH -> tanh else sigmoid, store fp16 (gates)
// MODE 1: plain store fp16
template<int MODE>
__global__ __launch_bounds__(256)
void gemm_lds(const _Float16* __restrict__ A, const _Float16* __restrict__ Bm,
              const float* __restrict__ bias, _Float16* __restrict__ C,
              int N, int K, int HH)
{
    __shared__ __align__(16) _Float16 sA[128][32];  // linear: global_load_lds dest
    __shared__ __align__(16) _Float16 sB[128][32];  // is lane-ordered (no padding)

    const int tid  = threadIdx.x;
    const int lane = tid & 63;
    const int wave = tid >> 6;
    const int wm = wave >> 1;          // wave row (0..1)
    const int wn = wave & 1;           // wave col (0..1)
    const size_t row0 = (size_t)blockIdx.y * 128;
    const size_t col0 = (size_t)blockIdx.x * 128;

    // staging: chunk = 16 rows = 1024 B (64 lanes x 16 B). wave stages chunks
    // {2*wave, 2*wave+1} of A and B. lane l -> row (l>>2), col fp16 (l&3)*8.
    const int crow = lane >> 2;
    const int ccol = (lane & 3) * 8;

    f32x4 acc[4][4] = {};

    const int rl = lane & 15;          // fragment row (A) / col (B)
    const int kb = (lane >> 4) * 8;    // fp16 k-offset within 32-wide row

    const int nk = K / 32;
    for (int kt = 0; kt < nk; ++kt) {
        // ---- stage tile kt into LDS (async, drains at the barrier) ----
#pragma unroll
        for (int c2 = 0; c2 < 2; ++c2) {
            const int c = wave * 2 + c2;               // chunk 0..7
            const _Float16* ga = A  + (row0 + c * 16 + crow) * (size_t)K + kt * 32 + ccol;
            const _Float16* gb = Bm + (col0 + c * 16 + crow) * (size_t)K + kt * 32 + ccol;
            __builtin_amdgcn_global_load_lds(AS1(ga), AS3(&sA[c * 16][0]), 16, 0, 0);
            __builtin_amdgcn_global_load_lds(AS1(gb), AS3(&sB[c * 16][0]), 16, 0, 0);
        }
        __syncthreads();

        // ---- LDS -> fragments, MFMA ----
        f16x8 af[4], bf[4];
#pragma unroll
        for (int m = 0; m < 4; ++m)
            af[m] = *(const f16x8*)&sA[wm * 64 + m * 16 + rl][kb];
#pragma unroll
        for (int n = 0; n < 4; ++n)
            bf[n] = *(const f16x8*)&sB[wn * 64 + n * 16 + rl][kb];
#pragma unroll
        for (int m = 0; m < 4; ++m)
#pragma unroll
            for (int n = 0; n < 4; ++n)
                acc[m][n] = __builtin_amdgcn_mfma_f32_16x16x32_f16(af[m], bf[n], acc[m][n], 0, 0, 0);
        __syncthreads();
    }

    // epilogue: C/D layout col=lane&15, row=(lane>>4)*4+reg  [measured m89]
#pragma unroll
    for (int m = 0; m < 4; ++m) {
#pragma unroll
        for (int n = 0; n < 4; ++n) {
            const size_t col = col0 + wn * 64 + n * 16 + rl;
            const size_t row = row0 + wm * 64 + m * 16 + (lane >> 4) * 4;
            float bv = (MODE == 0) ? bias[col] : 0.f;
#pragma unroll
            for (int j = 0; j < 4; ++j) {
                float v = acc[m][n][j];
                if (MODE == 0) {
                    v += bv;
                    if ((int)col < HH) {
                        float vc = fminf(fmaxf(v, -15.f), 15.f);   // clamp: no inf/NaN
                        float e = __expf(2.f * vc);
                        v = (e - 1.f) / (e + 1.f);                 // tanh
                    } else {
                        v = 1.f / (1.f + __expf(-v));              // sigmoid
                    }
                }
                C[(row + j) * (size_t)N + col] = (_Float16)v;
            }
        }
    }
}

// ---------------- forget-mult scan over one S-chunk ----------------
// Y: (nS*B, 3H) activated gates (z,f,o) fp16 for this chunk.
// Ho: (nS*B, H) fp16 = sigmoid(O)*C.  carry: (B*H) fp32 running state.
// first!=0 -> c starts at 0.  hid!=null -> also write final state there.
__global__ __launch_bounds__(64)
void scan_kernel(const _Float16* __restrict__ Y, _Float16* __restrict__ Ho,
                 float* __restrict__ carry, float* __restrict__ hid,
                 int nS, int first)
{
    const int t = blockIdx.x * 64 + threadIdx.x;  // 0..32767 = b*H + h
    const int h = t & (HID - 1);
    const int b = t >> 10;
    const _Float16* pz = Y + (size_t)b * G3H + h;
    _Float16* po = Ho + (size_t)b * HID + h;
    const size_t strideY = (size_t)BATCH * G3H;
    const size_t strideH = (size_t)BATCH * HID;
    float c = first ? 0.f : carry[t];
#pragma unroll 8
    for (int s = 0; s < nS; ++s) {
        float z = (float)pz[(size_t)s * strideY];
        float f = (float)pz[(size_t)s * strideY + HID];
        float o = (float)pz[(size_t)s * strideY + 2 * HID];
        c = f * z + (1.f - f) * c;
        po[(size_t)s * strideH] = (_Float16)(o * c);
    }
    carry[t] = c;
    if (hid) hid[t] = c;
}

// ---------------- LayerNorm over last dim (512) ----------------
// OUT32=0: write fp16 (feeds next layer GEMM); OUT32=1: write fp32 (final out)
template<int OUT32>
__global__ __launch_bounds__(256)
void ln_kernel(const _Float16* __restrict__ Xin, const float* __restrict__ g,
               const float* __restrict__ be, _Float16* __restrict__ o16,
               float* __restrict__ o32)
{
    const int row  = blockIdx.x * 4 + (threadIdx.x >> 6);
    const int lane = threadIdx.x & 63;
    const _Float16* p = Xin + (size_t)row * PROJ + lane * 8;
    f16x8 v = *(const f16x8*)p;
    float x[8];
    float s = 0.f;
#pragma unroll
    for (int j = 0; j < 8; ++j) { x[j] = (float)v[j]; s += x[j]; }
#pragma unroll
    for (int d = 1; d < 64; d <<= 1) s += __shfl_xor(s, d);
    const float mu = s * (1.f / PROJ);
    float s2 = 0.f;
#pragma unroll
    for (int j = 0; j < 8; ++j) { float dd = x[j] - mu; s2 += dd * dd; }
#pragma unroll
    for (int d = 1; d < 64; d <<= 1) s2 += __shfl_xor(s2, d);
    const float rstd = rsqrtf(s2 * (1.f / PROJ) + 1e-5f);

    float y[8];
#pragma unroll
    for (int j = 0; j < 8; ++j)
        y[j] = (x[j] - mu) * rstd * g[lane * 8 + j] + be[lane * 8 + j];

    if (OUT32) {
        float* q = o32 + (size_t)row * PROJ + lane * 8;
        ((float4*)q)[0] = make_float4(y[0], y[1], y[2], y[3]);
        ((float4*)q)[1] = make_float4(y[4], y[5], y[6], y[7]);
    } else {
        f16x8 o;
#pragma unroll
        for (int j = 0; j < 8; ++j) o[j] = (_Float16)y[j];
        *(f16x8*)(o16 + (size_t)row * PROJ + lane * 8) = o;
    }
}

// ---------------- launch ----------------
extern "C" void kernel_launch(void* const* d_in, const int* in_sizes, int n_in,
                              void* d_out, int out_size, void* d_ws, size_t ws_size,
                              hipStream_t stream)
{
    const float* X     = (const float*)d_in[0];
    const float* W     = (const float*)d_in[1];
    const float* b     = (const float*)d_in[2];
    const float* P     = (const float*)d_in[3];
    const float* gamma = (const float*)d_in[4];
    const float* beta  = (const float*)d_in[5];
    float* out = (float*)d_out;

    // ---- ws layout: fixed buffers, then S-chunked transient buffers ----
    char* w = (char*)d_ws;
    _Float16* Xh = (_Float16*)w; w += (size_t)ROWS * DIN * 2;     // 64 MiB; layer-0 input, then layer-1 input (aliased)
    _Float16* Wh = (_Float16*)w; w += (size_t)2 * G3H * DIN * 2;  // 6 MiB
    _Float16* Ph = (_Float16*)w; w += (size_t)2 * PROJ * HID * 2; // 2 MiB
    float* carry = (float*)w;    w += (size_t)BATCH * HID * 4;    // 128 KiB scan state
    const size_t fixed = (size_t)(w - (char*)d_ws);

    // pick largest S-chunk that fits ws: per-chunk = CS*32*(3H+H+PROJ)*2 bytes
    const int cands[7] = {2048, 1024, 512, 256, 128, 64, 32};
    int CS = 32;
    for (int i = 0; i < 7; ++i) {
        size_t need = fixed + (size_t)cands[i] * 32 * (G3H + HID + PROJ) * 2;
        if (need <= ws_size) { CS = cands[i]; break; }
    }
    _Float16* Yg = (_Float16*)w; w += (size_t)CS * 32 * G3H * 2;  // gates chunk
    _Float16* Ho = (_Float16*)w; w += (size_t)CS * 32 * HID * 2;  // gated output chunk
    _Float16* G2 = (_Float16*)w;                                   // proj chunk

    cvt_f32_f16<<<(ROWS * DIN / 4 + 255) / 256, 256, 0, stream>>>(X, Xh, ROWS * DIN / 4);
    cvt_f32_f16<<<(2 * G3H * DIN / 4 + 255) / 256, 256, 0, stream>>>(W, Wh, 2 * G3H * DIN / 4);
    cvt_f32_f16<<<(2 * PROJ * HID / 4 + 255) / 256, 256, 0, stream>>>(P, Ph, 2 * PROJ * HID / 4);

    float* hid = out + (size_t)ROWS * PROJ;   // next_hidden region of d_out
    const int nch = SEQ / CS;
    const int rows = CS * BATCH;              // rows per chunk (multiple of 128)

    for (int i = 0; i < 2; ++i) {
        for (int ch = 0; ch < nch; ++ch) {
            const size_t r0 = (size_t)ch * rows;
            // gates = act(inp @ W[i]^T + b[i])
            gemm_lds<0><<<dim3(G3H / 128, rows / 128), 256, 0, stream>>>(
                Xh + r0 * DIN, Wh + (size_t)i * G3H * DIN, b + i * G3H, Yg, G3H, DIN, HID);
            // forget-mult scan chunk (+ output gate); last chunk writes next_hidden
            scan_kernel<<<(BATCH * HID) / 64, 64, 0, stream>>>(
                Yg, Ho, carry, (ch == nch - 1) ? hid + (size_t)i * BATCH * HID : nullptr,
                CS, ch == 0);
            // projection
            gemm_lds<1><<<dim3(PROJ / 128, rows / 128), 256, 0, stream>>>(
                Ho, Ph + (size_t)i * PROJ * HID, nullptr, G2, PROJ, HID, 0);
            // layernorm: layer 0 -> fp16 back into Xh (next layer input, safe:
            // GEMM1 of this chunk already consumed these rows; later chunks untouched)
            if (i == 0)
                ln_kernel<0><<<rows / 4, 256, 0, stream>>>(G2, gamma, beta, Xh + r0 * PROJ, nullptr);
            else
                ln_kernel<1><<<rows / 4, 256, 0, stream>>>(G2, gamma + PROJ, beta + PROJ, nullptr, out + r0 * PROJ);
        }
    }
}

// Round 5
// 1590.449 us; speedup vs baseline: 1.1678x; 1.1678x over previous
//
#include <hip/hip_runtime.h>
#include <hip/hip_bf16.h>

// ---- types ----
typedef _Float16 f16x8 __attribute__((ext_vector_type(8)));
typedef _Float16 f16x4 __attribute__((ext_vector_type(4)));
typedef float f32x4 __attribute__((ext_vector_type(4)));

// Problem constants: S=2048, B=32, D_IN=512, H=1024, PROJ=512, L=2
#define SEQ 2048
#define BATCH 32
#define DIN 512
#define HID 1024
#define PROJ 512
#define ROWS (SEQ*BATCH)          // 65536
#define G3H (3*HID)               // 3072
#define NSEG 16
#define NCHAIN (BATCH*HID)        // 32768 scan chains

#define AS1(p) ((const __attribute__((address_space(1))) void*)(p))
#define AS3(p) ((__attribute__((address_space(3))) void*)(p))

// ---------------- fp32 -> fp16 conversion ----------------
__global__ __launch_bounds__(256)
void cvt_f32_f16(const float* __restrict__ in, _Float16* __restrict__ out, int n4)
{
    int i = blockIdx.x * 256 + threadIdx.x;
    if (i >= n4) return;
    float4 v = ((const float4*)in)[i];
    f16x4 o;
    o[0] = (_Float16)v.x; o[1] = (_Float16)v.y;
    o[2] = (_Float16)v.z; o[3] = (_Float16)v.w;
    ((f16x4*)out)[i] = o;
}

// ---------------- GEMM: C(M,N) = A(M,K) * B(N,K)^T, fp16 in, fp32 acc ------
// m97 structure + 2-phase prefetch: double-buffered linear LDS, stage tile
// kt+1 via global_load_lds while MFMAing tile kt; one barrier per tile
// (syncthreads drains vmcnt -> stage complete, lgkm -> ds_reads done).
// MODE 0: epilogue +bias, col<HH -> tanh else sigmoid, store fp16 (gates)
// MODE 1: plain store fp16
template<int MODE>
__global__ __launch_bounds__(256)
void gemm_lds(const _Float16* __restrict__ A, const _Float16* __restrict__ Bm,
              const float* __restrict__ bias, _Float16* __restrict__ C,
              int N, int K, int HH)
{
    __shared__ __align__(16) _Float16 sA[2][128][32];  // 16 KiB
    __shared__ __align__(16) _Float16 sB[2][128][32];  // 16 KiB

    const int tid  = threadIdx.x;
    const int lane = tid & 63;
    const int wave = tid >> 6;
    const int wm = wave >> 1;
    const int wn = wave & 1;
    const size_t row0 = (size_t)blockIdx.y * 128;
    const size_t col0 = (size_t)blockIdx.x * 128;

    // staging: chunk = 16 rows = 1024 B (64 lanes x 16 B); wave stages chunks
    // {2w, 2w+1} of A and B. lane l -> row (l>>2), col (l&3)*8.
    const int crow = lane >> 2;
    const int ccol = (lane & 3) * 8;

    f32x4 acc[4][4] = {};

    const int rl = lane & 15;
    const int kb = (lane >> 4) * 8;
    const int nk = K / 32;

    const int c0 = wave * 2, c1 = wave * 2 + 1;
    const _Float16* gA0 = A  + (row0 + c0 * 16 + crow) * (size_t)K + ccol;
    const _Float16* gA1 = A  + (row0 + c1 * 16 + crow) * (size_t)K + ccol;
    const _Float16* gB0 = Bm + (col0 + c0 * 16 + crow) * (size_t)K + ccol;
    const _Float16* gB1 = Bm + (col0 + c1 * 16 + crow) * (size_t)K + ccol;

#define STAGE(buf, kt)                                                          \
    do {                                                                        \
        __builtin_amdgcn_global_load_lds(AS1(gA0 + (size_t)(kt) * 32),          \
                                         AS3(&sA[buf][c0 * 16][0]), 16, 0, 0);  \
        __builtin_amdgcn_global_load_lds(AS1(gB0 + (size_t)(kt) * 32),          \
                                         AS3(&sB[buf][c0 * 16][0]), 16, 0, 0);  \
        __builtin_amdgcn_global_load_lds(AS1(gA1 + (size_t)(kt) * 32),          \
                                         AS3(&sA[buf][c1 * 16][0]), 16, 0, 0);  \
        __builtin_amdgcn_global_load_lds(AS1(gB1 + (size_t)(kt) * 32),          \
                                         AS3(&sB[buf][c1 * 16][0]), 16, 0, 0);  \
    } while (0)

    int cur = 0;
    STAGE(0, 0);
    __syncthreads();

    for (int kt = 0; kt < nk; ++kt) {
        if (kt + 1 < nk) STAGE(cur ^ 1, kt + 1);
        f16x8 af[4], bf[4];
#pragma unroll
        for (int m = 0; m < 4; ++m)
            af[m] = *(const f16x8*)&sA[cur][wm * 64 + m * 16 + rl][kb];
#pragma unroll
        for (int n = 0; n < 4; ++n)
            bf[n] = *(const f16x8*)&sB[cur][wn * 64 + n * 16 + rl][kb];
#pragma unroll
        for (int m = 0; m < 4; ++m)
#pragma unroll
            for (int n = 0; n < 4; ++n)
                acc[m][n] = __builtin_amdgcn_mfma_f32_16x16x32_f16(af[m], bf[n], acc[m][n], 0, 0, 0);
        __syncthreads();   // drains vmcnt (stage kt+1 done) + all ds_reads
        cur ^= 1;
    }
#undef STAGE

    // epilogue: C/D layout col=lane&15, row=(lane>>4)*4+reg  [measured m89]
#pragma unroll
    for (int m = 0; m < 4; ++m) {
#pragma unroll
        for (int n = 0; n < 4; ++n) {
            const size_t col = col0 + wn * 64 + n * 16 + rl;
            const size_t row = row0 + wm * 64 + m * 16 + (lane >> 4) * 4;
            float bv = (MODE == 0) ? bias[col] : 0.f;
#pragma unroll
            for (int j = 0; j < 4; ++j) {
                float v = acc[m][n][j];
                if (MODE == 0) {
                    v += bv;
                    if ((int)col < HH) {
                        float vc = fminf(fmaxf(v, -15.f), 15.f);
                        float e = __expf(2.f * vc);
                        v = __fdividef(e - 1.f, e + 1.f);          // tanh
                    } else {
                        v = __fdividef(1.f, 1.f + __expf(-v));     // sigmoid
                    }
                }
                C[(row + j) * (size_t)N + col] = (_Float16)v;
            }
        }
    }
}

// ============ segmented forget-mult scan (3 kernels) =======================
// chain t = b*H + h (32768). Chunk of nS steps split into NSEG segments of
// SL = nS/NSEG. Affine composition: over a segment, c_out = A*c_in + B with
// A = prod(1-f), B = local scan from 0. Exact in fp32 (same arithmetic).

// pass1: per (chain, seg): compute A,B from z,f gates.
__global__ __launch_bounds__(256)
void scan_p1(const _Float16* __restrict__ Y, float* __restrict__ Aseg,
             float* __restrict__ Bseg, int SL)
{
    const int t = blockIdx.x * 256 + threadIdx.x;
    const int g = blockIdx.y;
    const int h = t & (HID - 1);
    const int b = t >> 10;
    const _Float16* pz = Y + ((size_t)(g * SL) * BATCH + b) * G3H + h;
    const size_t strideY = (size_t)BATCH * G3H;
    float A = 1.f, Bv = 0.f;
#pragma unroll 4
    for (int k = 0; k < SL; ++k) {
        float z = (float)pz[0];
        float f = (float)pz[HID];
        Bv = f * z + (1.f - f) * Bv;
        A *= (1.f - f);
        pz += strideY;
    }
    Aseg[(size_t)g * NCHAIN + t] = A;
    Bseg[(size_t)g * NCHAIN + t] = Bv;
}

// mid: per chain: 16-step scan over segments -> c_start per segment;
// also advances the chunk carry and (optionally) writes next_hidden.
__global__ __launch_bounds__(256)
void scan_mid(const float* __restrict__ Aseg, const float* __restrict__ Bseg,
              float* __restrict__ cst, float* __restrict__ carry,
              float* __restrict__ hid, int first)
{
    const int t = blockIdx.x * 256 + threadIdx.x;
    float c = first ? 0.f : carry[t];
#pragma unroll
    for (int g = 0; g < NSEG; ++g) {
        cst[(size_t)g * NCHAIN + t] = c;
        c = Bseg[(size_t)g * NCHAIN + t] + Aseg[(size_t)g * NCHAIN + t] * c;
    }
    carry[t] = c;
    if (hid) hid[t] = c;
}

// pass2: per (chain, seg): redo local scan with known c_start, apply output
// gate, write Ho.
__global__ __launch_bounds__(256)
void scan_p2(const _Float16* __restrict__ Y, const float* __restrict__ cst,
             _Float16* __restrict__ Ho, int SL)
{
    const int t = blockIdx.x * 256 + threadIdx.x;
    const int g = blockIdx.y;
    const int h = t & (HID - 1);
    const int b = t >> 10;
    const _Float16* pz = Y + ((size_t)(g * SL) * BATCH + b) * G3H + h;
    _Float16* po = Ho + ((size_t)(g * SL) * BATCH + b) * HID + h;
    const size_t strideY = (size_t)BATCH * G3H;
    const size_t strideH = (size_t)BATCH * HID;
    float c = cst[(size_t)g * NCHAIN + t];
#pragma unroll 4
    for (int k = 0; k < SL; ++k) {
        float z = (float)pz[0];
        float f = (float)pz[HID];
        float o = (float)pz[2 * HID];
        c = f * z + (1.f - f) * c;
        *po = (_Float16)(o * c);
        pz += strideY;
        po += strideH;
    }
}

// ---------------- LayerNorm over last dim (512) ----------------
template<int OUT32>
__global__ __launch_bounds__(256)
void ln_kernel(const _Float16* __restrict__ Xin, const float* __restrict__ g,
               const float* __restrict__ be, _Float16* __restrict__ o16,
               float* __restrict__ o32)
{
    const int row  = blockIdx.x * 4 + (threadIdx.x >> 6);
    const int lane = threadIdx.x & 63;
    const _Float16* p = Xin + (size_t)row * PROJ + lane * 8;
    f16x8 v = *(const f16x8*)p;
    float x[8];
    float s = 0.f;
#pragma unroll
    for (int j = 0; j < 8; ++j) { x[j] = (float)v[j]; s += x[j]; }
#pragma unroll
    for (int d = 1; d < 64; d <<= 1) s += __shfl_xor(s, d);
    const float mu = s * (1.f / PROJ);
    float s2 = 0.f;
#pragma unroll
    for (int j = 0; j < 8; ++j) { float dd = x[j] - mu; s2 += dd * dd; }
#pragma unroll
    for (int d = 1; d < 64; d <<= 1) s2 += __shfl_xor(s2, d);
    const float rstd = rsqrtf(s2 * (1.f / PROJ) + 1e-5f);

    float y[8];
#pragma unroll
    for (int j = 0; j < 8; ++j)
        y[j] = (x[j] - mu) * rstd * g[lane * 8 + j] + be[lane * 8 + j];

    if (OUT32) {
        float* q = o32 + (size_t)row * PROJ + lane * 8;
        ((float4*)q)[0] = make_float4(y[0], y[1], y[2], y[3]);
        ((float4*)q)[1] = make_float4(y[4], y[5], y[6], y[7]);
    } else {
        f16x8 o;
#pragma unroll
        for (int j = 0; j < 8; ++j) o[j] = (_Float16)y[j];
        *(f16x8*)(o16 + (size_t)row * PROJ + lane * 8) = o;
    }
}

// ---------------- launch ----------------
extern "C" void kernel_launch(void* const* d_in, const int* in_sizes, int n_in,
                              void* d_out, int out_size, void* d_ws, size_t ws_size,
                              hipStream_t stream)
{
    const float* X     = (const float*)d_in[0];
    const float* W     = (const float*)d_in[1];
    const float* b     = (const float*)d_in[2];
    const float* P     = (const float*)d_in[3];
    const float* gamma = (const float*)d_in[4];
    const float* beta  = (const float*)d_in[5];
    float* out = (float*)d_out;

    // ---- ws layout: fixed buffers, then S-chunked transient buffers ----
    char* w = (char*)d_ws;
    _Float16* Xh = (_Float16*)w; w += (size_t)ROWS * DIN * 2;     // 64 MiB (layer input, aliased across layers)
    _Float16* Wh = (_Float16*)w; w += (size_t)2 * G3H * DIN * 2;  // 6 MiB
    _Float16* Ph = (_Float16*)w; w += (size_t)2 * PROJ * HID * 2; // 2 MiB
    float* carry = (float*)w;    w += (size_t)NCHAIN * 4;         // 128 KiB
    float* Aseg  = (float*)w;    w += (size_t)NSEG * NCHAIN * 4;  // 2 MiB
    float* Bseg  = (float*)w;    w += (size_t)NSEG * NCHAIN * 4;  // 2 MiB
    float* cst   = (float*)w;    w += (size_t)NSEG * NCHAIN * 4;  // 2 MiB
    const size_t fixed = (size_t)(w - (char*)d_ws);

    // largest S-chunk that fits: per-chunk = CS*32*(3H+H+PROJ)*2 bytes
    const int cands[7] = {2048, 1024, 512, 256, 128, 64, 32};
    int CS = 32;
    for (int i = 0; i < 7; ++i) {
        size_t need = fixed + (size_t)cands[i] * 32 * (G3H + HID + PROJ) * 2;
        if (need <= ws_size) { CS = cands[i]; break; }
    }
    _Float16* Yg = (_Float16*)w; w += (size_t)CS * 32 * G3H * 2;  // gates chunk
    _Float16* Ho = (_Float16*)w; w += (size_t)CS * 32 * HID * 2;  // gated output chunk
    _Float16* G2 = (_Float16*)w;                                   // proj chunk

    cvt_f32_f16<<<(ROWS * DIN / 4 + 255) / 256, 256, 0, stream>>>(X, Xh, ROWS * DIN / 4);
    cvt_f32_f16<<<(2 * G3H * DIN / 4 + 255) / 256, 256, 0, stream>>>(W, Wh, 2 * G3H * DIN / 4);
    cvt_f32_f16<<<(2 * PROJ * HID / 4 + 255) / 256, 256, 0, stream>>>(P, Ph, 2 * PROJ * HID / 4);

    float* hid = out + (size_t)ROWS * PROJ;   // next_hidden region of d_out
    const int nch = SEQ / CS;
    const int rows = CS * BATCH;              // rows per chunk (multiple of 128)
    const int SL = CS / NSEG;                 // segment length

    for (int i = 0; i < 2; ++i) {
        for (int ch = 0; ch < nch; ++ch) {
            const size_t r0 = (size_t)ch * rows;
            // gates = act(inp @ W[i]^T + b[i])
            gemm_lds<0><<<dim3(G3H / 128, rows / 128), 256, 0, stream>>>(
                Xh + r0 * DIN, Wh + (size_t)i * G3H * DIN, b + i * G3H, Yg, G3H, DIN, HID);
            // segmented forget-mult scan
            scan_p1<<<dim3(NCHAIN / 256, NSEG), 256, 0, stream>>>(Yg, Aseg, Bseg, SL);
            scan_mid<<<NCHAIN / 256, 256, 0, stream>>>(
                Aseg, Bseg, cst, carry,
                (ch == nch - 1) ? hid + (size_t)i * NCHAIN : nullptr, ch == 0);
            scan_p2<<<dim3(NCHAIN / 256, NSEG), 256, 0, stream>>>(Yg, cst, Ho, SL);
            // projection
            gemm_lds<1><<<dim3(PROJ / 128, rows / 128), 256, 0, stream>>>(
                Ho, Ph + (size_t)i * PROJ * HID, nullptr, G2, PROJ, HID, 0);
            // layernorm: layer 0 -> fp16 back into Xh (rows already consumed)
            if (i == 0)
                ln_kernel<0><<<rows / 4, 256, 0, stream>>>(G2, gamma, beta, Xh + r0 * PROJ, nullptr);
            else
                ln_kernel<1><<<rows / 4, 256, 0, stream>>>(G2, gamma + PROJ, beta + PROJ, nullptr, out + r0 * PROJ);
        }
    }
}